// Round 14
// baseline (995.624 us; speedup 1.0000x reference)
//
#include <hip/hip_runtime.h>
#include <hip/hip_bf16.h>

typedef __hip_bfloat16 bf16;
typedef __attribute__((ext_vector_type(8))) short short8;   // 8 bf16 MFMA frag
typedef __attribute__((ext_vector_type(4))) float f32x4;
typedef __attribute__((ext_vector_type(4))) int  int4v;

constexpr int Bc = 2, Sc = 256, Dc = 1024, Hc = 8, DKc = 128, Fc = 4096, Lc = 8, Kc = 37;
constexpr float SCALE = 0.08838834764831845f; // 1/sqrt(128)

#define WAITV6 asm volatile("s_waitcnt vmcnt(6)" ::: "memory")
#define WAITV0 asm volatile("s_waitcnt vmcnt(0)" ::: "memory")
#define SBAR() do { __builtin_amdgcn_sched_barrier(0); __builtin_amdgcn_s_barrier(); } while (0)

// ---------------------------------------------------------------------------
__global__ __launch_bounds__(256) void detect_k(const unsigned short* __restrict__ w,
                                                int* __restrict__ flag) {
    __shared__ int cnt;
    if (threadIdx.x == 0) cnt = 0;
    __syncthreads();
    int ok = 0;
    #pragma unroll
    for (int j = 0; j < 16; j++) {
        unsigned short u = w[threadIdx.x * 16 + j];
        int e = (u >> 7) & 0xFF;
        ok += (e >= 100 && e <= 131) ? 1 : 0;
    }
    atomicAdd(&cnt, ok);
    __syncthreads();
    if (threadIdx.x == 0) *flag = (cnt < 3500) ? 1 : 0;  // 1 => external f32
}

__device__ __forceinline__ float ldf(const void* p, size_t i, bool f32) {
    return f32 ? ((const float*)p)[i] : __bfloat162float(((const bf16*)p)[i]);
}

// async global->LDS, 16B/lane; LDS base wave-uniform, lanes land linearly
__device__ __forceinline__ void gld16(const bf16* g, bf16* l) {
    __builtin_amdgcn_global_load_lds((const __attribute__((address_space(1))) void*)g,
                                     (__attribute__((address_space(3))) void*)l, 16, 0, 0);
}

// ---------------------------------------------------------------------------
__global__ __launch_bounds__(256) void cast_k(const void* __restrict__ x, float* __restrict__ h,
                                              const int* __restrict__ flagp) {
    bool f32 = (*flagp != 0);
    size_t i = (size_t)blockIdx.x * 256 + threadIdx.x;
    h[i] = ldf(x, i, f32);
}

// ---------------------------------------------------------------------------
// LayerNorm f32 rows(1024) -> bf16 (or external dtype when outExt)
__global__ __launch_bounds__(256) void ln_k(const float* __restrict__ in,
                                            const void* __restrict__ g, size_t goff,
                                            const void* __restrict__ be, size_t boff,
                                            void* __restrict__ out, int outExt,
                                            const int* __restrict__ flagp) {
    bool f32 = (*flagp != 0);
    int row = blockIdx.x, tid = threadIdx.x;
    const float* rp = in + (size_t)row * Dc;
    float4 v = *(const float4*)(rp + tid * 4);
    float s  = v.x + v.y + v.z + v.w;
    float sq = v.x * v.x + v.y * v.y + v.z * v.z + v.w * v.w;
    int w = tid >> 6, lane = tid & 63;
    #pragma unroll
    for (int off = 32; off >= 1; off >>= 1) {
        s  += __shfl_down(s, off);
        sq += __shfl_down(sq, off);
    }
    __shared__ float rs[4], rq[4];
    if (lane == 0) { rs[w] = s; rq[w] = sq; }
    __syncthreads();
    float S4 = rs[0] + rs[1] + rs[2] + rs[3];
    float Q4 = rq[0] + rq[1] + rq[2] + rq[3];
    float mean = S4 * (1.f / Dc);
    float var  = Q4 * (1.f / Dc) - mean * mean;
    float rstd = rsqrtf(var + 1e-5f);
    #pragma unroll
    for (int j = 0; j < 4; j++) {
        int c = tid * 4 + j;
        float xv = (&v.x)[j];
        float val = (xv - mean) * rstd * ldf(g, goff + c, f32) + ldf(be, boff + c, f32);
        size_t idx = (size_t)row * Dc + c;
        if (outExt && f32) ((float*)out)[idx] = val;
        else               ((bf16*)out)[idx] = __float2bfloat16(val);
    }
}

// ---------------------------------------------------------------------------
// Weight transpose+convert into BLOCKED PRE-SWIZZLED layout:
// W_t = [nTile][kTile][64n][64k], granule g of inner row n at slot g^(n&7).
// Each wave writes one fully contiguous 8KB tile. Read: 512B runs (64k x 256n).
// x-blocks: 0..255 Wq/Wk/Wv/Wo; 256..511 W1; 512..767 W2;
// 768: rel_k -> rkb [64][128] pad0, rel_v -> rvt [128][64] transposed pad0.
__global__ __launch_bounds__(256) void conv_k(const void* __restrict__ Wq, const void* __restrict__ Wk,
                                              const void* __restrict__ Wv, const void* __restrict__ Wo,
                                              const void* __restrict__ W1, const void* __restrict__ W2,
                                              const void* __restrict__ rk, const void* __restrict__ rv,
                                              char* __restrict__ slotBase, size_t slotStride,
                                              int layer0, int slotMul,
                                              const int* __restrict__ flagp) {
    bool f32 = (*flagp != 0);
    int l = layer0 + blockIdx.y;
    char* sp = slotBase + (size_t)(slotMul ? l : 0) * slotStride;
    bf16* Wqkv_t = (bf16*)sp;
    bf16* Wo_t   = (bf16*)(sp + (6ll << 20));
    bf16* W1_t   = (bf16*)(sp + (8ll << 20));
    bf16* W2_t   = (bf16*)(sp + (16ll << 20));
    bf16* rkb    = (bf16*)(sp + (24ll << 20));
    bf16* rvt    = (bf16*)(sp + (24ll << 20) + 16384);
    size_t wOff = (size_t)l * Dc * Dc, w1Off = (size_t)l * Dc * Fc, rOff = (size_t)l * Kc * DKc;

    int bid = blockIdx.x, tid = threadIdx.x;
    if (bid == 768) {
        for (int idx = tid; idx < 64 * DKc; idx += 256) {
            int rr = idx >> 7, d = idx & 127;
            rkb[idx] = (rr < Kc) ? __float2bfloat16(ldf(rk, rOff + (size_t)rr * DKc + d, f32))
                                 : __float2bfloat16(0.f);
        }
        for (int idx = tid; idx < DKc * 64; idx += 256) {
            int d = idx >> 6, rr = idx & 63;
            rvt[idx] = (rr < Kc) ? __float2bfloat16(ldf(rv, rOff + (size_t)rr * DKc + d, f32))
                                 : __float2bfloat16(0.f);
        }
        return;
    }
    const void* src; bf16* dst; int ldn, k0, n0, KT;
    if (bid < 256) {
        int m = bid >> 6, t = bid & 63;
        k0 = (t >> 2) * 64; n0 = (t & 3) * 256;
        src = (m == 0) ? Wq : (m == 1) ? Wk : (m == 2) ? Wv : Wo;
        src = (const void*)((const char*)src + wOff * (f32 ? 4 : 2));
        dst = (m < 3) ? (Wqkv_t + (size_t)m * Dc * Dc) : Wo_t;
        ldn = Dc; KT = 16;
    } else if (bid < 512) {
        int t = bid - 256;
        k0 = (t >> 4) * 64; n0 = (t & 15) * 256;
        src = (const void*)((const char*)W1 + w1Off * (f32 ? 4 : 2));
        dst = W1_t; ldn = Fc; KT = 16;
    } else {
        int t = bid - 512;
        k0 = (t >> 2) * 64; n0 = (t & 3) * 256;
        src = (const void*)((const char*)W2 + w1Off * (f32 ? 4 : 2));
        dst = W2_t; ldn = Dc; KT = 64;
    }
    __shared__ bf16 sT[64][264];
    int r = tid >> 2, seg = tid & 3;                 // k-row, 64-col segment
    if (f32) {
        const float* sp2 = (const float*)src + (size_t)(k0 + r) * ldn + n0 + seg * 64;
        #pragma unroll
        for (int c4 = 0; c4 < 4; c4++) {
            alignas(16) bf16 tmp[16];
            #pragma unroll
            for (int q = 0; q < 4; q++) {
                float4 fv = *(const float4*)(sp2 + c4 * 16 + q * 4);
                tmp[q * 4 + 0] = __float2bfloat16(fv.x);
                tmp[q * 4 + 1] = __float2bfloat16(fv.y);
                tmp[q * 4 + 2] = __float2bfloat16(fv.z);
                tmp[q * 4 + 3] = __float2bfloat16(fv.w);
            }
            *(int4v*)&sT[r][seg * 64 + c4 * 16]     = *(int4v*)tmp;
            *(int4v*)&sT[r][seg * 64 + c4 * 16 + 8] = *(int4v*)(tmp + 8);
        }
    } else {
        const bf16* sp2 = (const bf16*)src + (size_t)(k0 + r) * ldn + n0 + seg * 64;
        #pragma unroll
        for (int c4 = 0; c4 < 4; c4++) {
            *(int4v*)&sT[r][seg * 64 + c4 * 16]     = *(const int4v*)(sp2 + c4 * 16);
            *(int4v*)&sT[r][seg * 64 + c4 * 16 + 8] = *(const int4v*)(sp2 + c4 * 16 + 8);
        }
    }
    __syncthreads();
    // write: wave per 8KB dest tile, thread -> inner row n (128B, granule-permuted)
    int nt_i = tid >> 6, n = tid & 63;
    bf16* tileB = dst + ((((size_t)(n0 >> 6) + nt_i) * KT + (k0 >> 6)) << 12);
    alignas(16) bf16 outv[64];
    #pragma unroll
    for (int k = 0; k < 64; k++) outv[k] = sT[k][tid];
    bf16* dp = tileB + n * 64;
    #pragma unroll
    for (int g = 0; g < 8; g++)
        *(int4v*)(dp + ((g ^ (n & 7)) << 3)) = *(int4v*)(outv + g * 8);
}

// ---------------------------------------------------------------------------
// swizzled frag read: granule g at row r lives at slot g ^ (r&7)
__device__ __forceinline__ short8 frd(const bf16* s, int row, int g) {
    return *(const short8*)(s + (size_t)row * 64 + ((g ^ (row & 7)) << 3));
}

// 64m x 128n tile MFMA GEMM, BK=64, 2-buf (m97-style 2 barriers/step) with
// counted vmcnt(6). Wave = 32m x 64n (2x4 acc): 16 MFMA / 12 ds_read per step.
// A [m][k] row-major via source-swizzled gld16; B blocked pre-swizzled
// [n64Tile][KT][64][64] -> fully linear gld16 staging (2 tiles per 128n).
// 1-D grid, XCD-aware bijective decomposition (nx % 8 == 0).
// MODE 0: qkv cols<2048 -> qkv+bias; cols>=2048 -> vt transposed (+bias)
// MODE 1: outb = relu(A@B^T + bias)
// MODE 2: atomicAdd(outf, A@B^T + (kslice==0 ? bias : 0))
template <int MODE>
__global__ __launch_bounds__(256) void gemm2_k(const bf16* __restrict__ Ag, int lda,
                                               const bf16* __restrict__ Bt, int KT,
                                               const void* __restrict__ bA, const void* __restrict__ bB,
                                               const void* __restrict__ bC, size_t boff,
                                               float* __restrict__ outf,
                                               bf16* __restrict__ outb, bf16* __restrict__ vtp,
                                               int N, int Kd, int nx, int znum,
                                               const int* __restrict__ flagp) {
    bool f32e = (*flagp != 0);
    __shared__ bf16 sA[2][64][64];
    __shared__ bf16 sB[2][128][64];
    int tid = threadIdx.x, wv = tid >> 6, lane = tid & 63;

    // XCD-aware bijective decomposition (nx % 8 == 0 required)
    int bid = blockIdx.x;
    int c = bid & 7, j = bid >> 3;
    int npc = nx >> 3;
    int mz = 8 * znum;
    int nl = j / mz; int rem = j - nl * mz;
    int mtile = rem / znum; int kslice = rem - mtile * znum;
    int ntile = c * npc + nl;

    int row0 = mtile * 64;
    int nt = Kd / 64;
    int kbase = kslice * nt;
    const bf16* Ab = Ag + (size_t)kslice * Kd;
    int wm = (wv >> 1) * 32, wn = (wv & 1) * 64;
    int lr = lane >> 3;
    int gsw = ((lane & 7) ^ lr) * 8;        // A: swizzled source granule offset
    int lc8 = (lane & 7) * 8;               // B: linear within blocked tile
    f32x4 acc[2][4] = {};

    auto stage = [&](int buf, int t) {
        #pragma unroll
        for (int cc = 0; cc < 2; ++cc) {    // A: 2 gld16
            int rr = 16 * wv + 8 * cc;
            gld16(Ab + (size_t)(row0 + rr + lr) * lda + t * 64 + gsw, &sA[buf][rr][0]);
        }
        #pragma unroll
        for (int cc = 0; cc < 4; ++cc) {    // B: 4 gld16 (two blocked tiles)
            int rr = 32 * wv + 8 * cc;
            const bf16* bt = Bt + (((size_t)(ntile * 2 + (rr >> 6)) * KT + kbase + t) << 12);
            gld16(bt + (size_t)((rr & 63) + lr) * 64 + lc8, &sB[buf][rr][0]);
        }
    };
    stage(0, 0);
    if (nt > 1) { stage(1, 1); WAITV6; } else { WAITV0; }
    SBAR();

    int r16 = lane & 15, kq = lane >> 4;
    for (int t = 0; t < nt; ++t) {
        int cb = t & 1;
        const bf16* pa = &sA[cb][0][0];
        const bf16* pb = &sB[cb][0][0];
        #pragma unroll
        for (int ks = 0; ks < 2; ks++) {
            int g = ks * 4 + kq;
            short8 a0 = frd(pa, wm + r16, g);
            short8 a1 = frd(pa, wm + 16 + r16, g);
            #pragma unroll
            for (int ni = 0; ni < 4; ni++) {
                short8 bf_ = frd(pb, wn + ni * 16 + r16, g);
                acc[0][ni] = __builtin_amdgcn_mfma_f32_16x16x32_bf16(a0, bf_, acc[0][ni], 0, 0, 0);
                acc[1][ni] = __builtin_amdgcn_mfma_f32_16x16x32_bf16(a1, bf_, acc[1][ni], 0, 0, 0);
            }
        }
        SBAR();                             // all waves done reading buf cb
        if (t + 2 < nt) { stage(cb, t + 2); WAITV6; }
        else if (t + 1 < nt) { WAITV0; }
        if (t + 1 < nt) SBAR();             // next buf ready
    }

    int col0 = ntile * 128;
    #pragma unroll
    for (int mi = 0; mi < 2; mi++) {
        #pragma unroll
        for (int ni = 0; ni < 4; ni++) {
            int col = col0 + wn + ni * 16 + r16;
            if (MODE == 0) {
                int sel = col >> 10;
                const void* bp = (sel == 0) ? bA : (sel == 1) ? bB : bC;
                float bias = ldf(bp, boff + (col & 1023), f32e);
                if (sel < 2) {
                    #pragma unroll
                    for (int r = 0; r < 4; r++) {
                        int row = row0 + wm + mi * 16 + kq * 4 + r;
                        outb[(size_t)row * 3072 + col] = __float2bfloat16(acc[mi][ni][r] + bias);
                    }
                } else {
                    int hh = (col - 2048) >> 7, d = (col - 2048) & 127;
                    int b = row0 >> 8;
                    int s0 = (row0 & 255) + wm + mi * 16 + kq * 4;
                    alignas(8) bf16 pk[4];
                    #pragma unroll
                    for (int r = 0; r < 4; r++) pk[r] = __float2bfloat16(acc[mi][ni][r] + bias);
                    *(short4*)(vtp + (((size_t)(b * 8 + hh)) * 128 + d) * 256 + s0) = *(short4*)pk;
                }
            } else if (MODE == 1) {
                float bias = ldf(bA, boff + col, f32e);
                #pragma unroll
                for (int r = 0; r < 4; r++) {
                    int row = row0 + wm + mi * 16 + kq * 4 + r;
                    float tv = acc[mi][ni][r] + bias;
                    outb[(size_t)row * N + col] = __float2bfloat16(tv > 0.f ? tv : 0.f);
                }
            } else {
                float add = (kslice == 0) ? ldf(bA, boff + col, f32e) : 0.f;
                #pragma unroll
                for (int r = 0; r < 4; r++) {
                    int row = row0 + wm + mi * 16 + kq * 4 + r;
                    atomicAdd(&outf[(size_t)row * N + col], acc[mi][ni][r] + add);
                }
            }
        }
    }
}

// ---------------------------------------------------------------------------
// Fused attention, ONE WAVE PER BLOCK (64 threads), 16 q-rows per block:
// grid (16 qgroups, 16 z) = 256 blocks -> all 256 CUs busy. T5 setprio
// around MFMA clusters (role-diverse blocks per CU).
__global__ __launch_bounds__(64) void attn_k(const bf16* __restrict__ qkv,
                                             const bf16* __restrict__ vt,
                                             const bf16* __restrict__ rkb,
                                             const bf16* __restrict__ rvt,
                                             const int* __restrict__ relation,
                                             bf16* __restrict__ ob) {
    int z = blockIdx.y, b = z >> 3, h = z & 7;
    int q0 = blockIdx.x * 16;
    int lane = threadIdx.x;
    int l15 = lane & 15, l4 = lane >> 4;

    __shared__ float qr_s[16][48];
    __shared__ float bins_s[16][40];
    __shared__ bf16  Pl[16][264];
    __shared__ bf16  binb[16][64];

    for (int c = lane; c < 16 * 40; c += 64) bins_s[c / 40][c % 40] = 0.f;

    short8 qf[4];
    const bf16* qp = qkv + (size_t)(b * Sc + q0 + l15) * 3072 + h * DKc + l4 * 8;
    #pragma unroll
    for (int ks = 0; ks < 4; ks++) qf[ks] = *(const short8*)(qp + ks * 32);

    f32x4 sc[19];
    #pragma unroll
    for (int f = 0; f < 19; f++) sc[f] = f32x4{0.f, 0.f, 0.f, 0.f};
    const bf16* kbase = qkv + (size_t)(b * Sc) * 3072 + Dc + h * DKc;
    __builtin_amdgcn_s_setprio(1);
    #pragma unroll
    for (int f = 0; f < 16; f++) {
        #pragma unroll
        for (int ks = 0; ks < 4; ks++) {
            short8 kv = *(const short8*)(kbase + (size_t)(f * 16 + l15) * 3072 + ks * 32 + l4 * 8);
            sc[f] = __builtin_amdgcn_mfma_f32_16x16x32_bf16(qf[ks], kv, sc[f], 0, 0, 0);
        }
    }
    #pragma unroll
    for (int f = 0; f < 3; f++) {
        #pragma unroll
        for (int ks = 0; ks < 4; ks++) {
            short8 rv_ = *(const short8*)(rkb + (size_t)(f * 16 + l15) * DKc + ks * 32 + l4 * 8);
            sc[16 + f] = __builtin_amdgcn_mfma_f32_16x16x32_bf16(qf[ks], rv_, sc[16 + f], 0, 0, 0);
        }
    }
    __builtin_amdgcn_s_setprio(0);
    #pragma unroll
    for (int f = 0; f < 3; f++)
        #pragma unroll
        for (int r = 0; r < 4; r++)
            qr_s[l4 * 4 + r][f * 16 + l15] = sc[16 + f][r];
    __syncthreads();

    unsigned relpk[16];
    #pragma unroll
    for (int f = 0; f < 16; f++) {
        unsigned pk = 0;
        #pragma unroll
        for (int r = 0; r < 4; r++) {
            int rowl = l4 * 4 + r;
            int col = f * 16 + l15;
            int rel = relation[((size_t)b * Sc + q0 + rowl) * Sc + col];
            pk |= (unsigned)rel << (8 * r);
            sc[f][r] = (sc[f][r] + qr_s[rowl][rel]) * SCALE;
        }
        relpk[f] = pk;
    }
    float inv[4];
    #pragma unroll
    for (int r = 0; r < 4; r++) {
        float m = -3.0e38f;
        #pragma unroll
        for (int f = 0; f < 16; f++) m = fmaxf(m, sc[f][r]);
        m = fmaxf(m, __shfl_xor(m, 1)); m = fmaxf(m, __shfl_xor(m, 2));
        m = fmaxf(m, __shfl_xor(m, 4)); m = fmaxf(m, __shfl_xor(m, 8));
        float s = 0.f;
        #pragma unroll
        for (int f = 0; f < 16; f++) { float e = __expf(sc[f][r] - m); sc[f][r] = e; s += e; }
        s += __shfl_xor(s, 1); s += __shfl_xor(s, 2); s += __shfl_xor(s, 4); s += __shfl_xor(s, 8);
        inv[r] = 1.f / s;
    }
    #pragma unroll
    for (int f = 0; f < 16; f++) {
        #pragma unroll
        for (int r = 0; r < 4; r++) {
            int rowl = l4 * 4 + r;
            int col = f * 16 + l15;
            float p = sc[f][r] * inv[r];
            Pl[rowl][col] = __float2bfloat16(p);
            int rel = (relpk[f] >> (8 * r)) & 0xFF;
            atomicAdd(&bins_s[rowl][rel], p);
        }
    }
    __syncthreads();
    for (int c = lane; c < 16 * 64; c += 64) {
        int row = c >> 6, k = c & 63;
        binb[row][k] = __float2bfloat16((k < Kc) ? bins_s[row][k] : 0.f);
    }
    __syncthreads();

    f32x4 acc_o[8];
    #pragma unroll
    for (int df = 0; df < 8; df++) acc_o[df] = f32x4{0.f, 0.f, 0.f, 0.f};
    const bf16* vbase = vt + (size_t)z * DKc * Sc;
    __builtin_amdgcn_s_setprio(1);
    #pragma unroll
    for (int ks = 0; ks < 8; ks++) {
        short8 af = *(const short8*)&Pl[l15][ks * 32 + l4 * 8];
        #pragma unroll
        for (int df = 0; df < 8; df++) {
            short8 bv = *(const short8*)(vbase + (size_t)(df * 16 + l15) * Sc + ks * 32 + l4 * 8);
            acc_o[df] = __builtin_amdgcn_mfma_f32_16x16x32_bf16(af, bv, acc_o[df], 0, 0, 0);
        }
    }
    #pragma unroll
    for (int ks = 0; ks < 2; ks++) {
        short8 af = *(const short8*)&binb[l15][ks * 32 + l4 * 8];
        #pragma unroll
        for (int df = 0; df < 8; df++) {
            short8 bv = *(const short8*)(rvt + (size_t)(df * 16 + l15) * 64 + ks * 32 + l4 * 8);
            acc_o[df] = __builtin_amdgcn_mfma_f32_16x16x32_bf16(af, bv, acc_o[df], 0, 0, 0);
        }
    }
    __builtin_amdgcn_s_setprio(0);
    #pragma unroll
    for (int df = 0; df < 8; df++) {
        int col = df * 16 + l15;
        #pragma unroll
        for (int r = 0; r < 4; r++) {
            int rowl = l4 * 4 + r;
            ob[((size_t)(b * Sc + q0 + rowl) * Hc + h) * DKc + col] = __float2bfloat16(acc_o[df][r]);
        }
    }
}

// ---------------------------------------------------------------------------
extern "C" void kernel_launch(void* const* d_in, const int* in_sizes, int n_in,
                              void* d_out, int out_size, void* d_ws, size_t ws_size,
                              hipStream_t stream) {
    const void* x        = d_in[0];
    const int*  relation = (const int*)d_in[1];
    const void* Wq = d_in[3];  const void* bq = d_in[4];
    const void* Wk = d_in[5];  const void* bk = d_in[6];
    const void* Wv = d_in[7];  const void* bv = d_in[8];
    const void* Wo = d_in[9];  const void* bo = d_in[10];
    const void* g1 = d_in[11]; const void* be1 = d_in[12];
    const void* W1 = d_in[13]; const void* b1 = d_in[14];
    const void* W2 = d_in[15]; const void* b2 = d_in[16];
    const void* g2 = d_in[17]; const void* be2 = d_in[18];
    const void* relk = d_in[19]; const void* relv = d_in[20];
    const void* lnfg = d_in[21]; const void* lnfb = d_in[22];

    char* ws = (char*)d_ws;
    float* h    = (float*)(ws);                 // 2 MB
    bf16*  hn   = (bf16*)(ws + (2ll  << 20));   // 1 MB
    bf16*  qkv  = (bf16*)(ws + (3ll  << 20));   // 3 MB [512][3072] (v third unused)
    bf16*  vt   = (bf16*)(ws + (6ll  << 20));   // 1 MB [16][128][256]
    bf16*  ob   = (bf16*)(ws + (7ll  << 20));   // 1 MB
    bf16*  f1   = (bf16*)(ws + (8ll  << 20));   // 4 MB
    int*   flag = (int*)(ws + (12ll << 20));
    const size_t WBASE = 13ll << 20;
    const size_t WSTRIDE = 25ll << 20;          // per-layer transposed weights
    int nslot = (ws_size >= WBASE + 8 * WSTRIDE) ? 8 : 1;
    char* slotBase = ws + WBASE;
    // slot: Wqkv_t 6MB | Wo_t 2MB | W1_t 8MB | W2_t 8MB | rkb 16KB | rvt 16KB

    const int M = Bc * Sc; // 512

    detect_k<<<1, 256, 0, stream>>>((const unsigned short*)Wq, flag);
    cast_k<<<(Bc * Sc * Dc) / 256, 256, 0, stream>>>(x, h, flag);

    if (nslot == 8)
        conv_k<<<dim3(769, 8), 256, 0, stream>>>(Wq, Wk, Wv, Wo, W1, W2, relk, relv,
                                                 slotBase, WSTRIDE, 0, 1, flag);

    for (int l = 0; l < Lc; l++) {
        if (nslot == 1)
            conv_k<<<dim3(769, 1), 256, 0, stream>>>(Wq, Wk, Wv, Wo, W1, W2, relk, relv,
                                                     slotBase, WSTRIDE, l, 0, flag);
        char* sp = slotBase + (size_t)((nslot == 8) ? l : 0) * WSTRIDE;
        bf16* Wqkv_t = (bf16*)sp;
        bf16* Wo_t   = (bf16*)(sp + (6ll << 20));
        bf16* W1_t   = (bf16*)(sp + (8ll << 20));
        bf16* W2_t   = (bf16*)(sp + (16ll << 20));
        bf16* rkb    = (bf16*)(sp + (24ll << 20));
        bf16* rvt    = (bf16*)(sp + (24ll << 20) + 16384);
        size_t dOff = (size_t)l * Dc, fOff = (size_t)l * Fc;

        ln_k<<<M, 256, 0, stream>>>(h, g1, dOff, be1, dOff, hn, 0, flag);

        // QKV (+ fused V-transpose epilogue): 24 n128-tiles x 8 m-tiles = 192 blocks
        gemm2_k<0><<<192, 256, 0, stream>>>(hn, Dc, Wqkv_t, 16, bq, bk, bv, dOff,
                                            nullptr, qkv, vt, 3072, Dc, 24, 1, flag);

        // attention: 256 single-wave blocks (16 qgroups x 16 z)
        attn_k<<<dim3(16, 16), 64, 0, stream>>>(qkv, vt, rkb, rvt, relation, ob);

        // h += o @ Wo + bo   (8 n128 x 8 m x splitK4 = 256 blocks)
        gemm2_k<2><<<256, 256, 0, stream>>>(ob, Dc, Wo_t, 16, bo, nullptr, nullptr, dOff,
                                            h, nullptr, nullptr, Dc, 256, 8, 4, flag);

        ln_k<<<M, 256, 0, stream>>>(h, g2, dOff, be2, dOff, hn, 0, flag);

        // f1 = relu(hn @ W1 + b1): 32 n128 x 8 m = 256 blocks
        gemm2_k<1><<<256, 256, 0, stream>>>(hn, Dc, W1_t, 16, b1, nullptr, nullptr, fOff,
                                            nullptr, f1, nullptr, Fc, Dc, 32, 1, flag);

        // h += f1 @ W2 + b2  (8 n128 x 8 m x splitK4 = 256 blocks)
        gemm2_k<2><<<256, 256, 0, stream>>>(f1, Fc, W2_t, 64, b2, nullptr, nullptr, dOff,
                                            h, nullptr, nullptr, Dc, 1024, 8, 4, flag);
    }

    ln_k<<<M, 256, 0, stream>>>(h, lnfg, 0, lnfb, 0, d_out, 1, flag);
}

// Round 15
// 915.125 us; speedup vs baseline: 1.0880x; 1.0880x over previous
//
#include <hip/hip_runtime.h>
#include <hip/hip_bf16.h>

typedef __hip_bfloat16 bf16;
typedef __attribute__((ext_vector_type(8))) short short8;   // 8 bf16 MFMA frag
typedef __attribute__((ext_vector_type(4))) float f32x4;
typedef __attribute__((ext_vector_type(4))) int  int4v;

constexpr int Bc = 2, Sc = 256, Dc = 1024, Hc = 8, DKc = 128, Fc = 4096, Lc = 8, Kc = 37;
constexpr float SCALE = 0.08838834764831845f; // 1/sqrt(128)

#define WAITV4 asm volatile("s_waitcnt vmcnt(4)" ::: "memory")
#define WAITV0 asm volatile("s_waitcnt vmcnt(0)" ::: "memory")
#define SBAR() do { __builtin_amdgcn_sched_barrier(0); __builtin_amdgcn_s_barrier(); } while (0)

// ---------------------------------------------------------------------------
__global__ __launch_bounds__(256) void detect_k(const unsigned short* __restrict__ w,
                                                int* __restrict__ flag) {
    __shared__ int cnt;
    if (threadIdx.x == 0) cnt = 0;
    __syncthreads();
    int ok = 0;
    #pragma unroll
    for (int j = 0; j < 16; j++) {
        unsigned short u = w[threadIdx.x * 16 + j];
        int e = (u >> 7) & 0xFF;
        ok += (e >= 100 && e <= 131) ? 1 : 0;
    }
    atomicAdd(&cnt, ok);
    __syncthreads();
    if (threadIdx.x == 0) *flag = (cnt < 3500) ? 1 : 0;  // 1 => external f32
}

__device__ __forceinline__ float ldf(const void* p, size_t i, bool f32) {
    return f32 ? ((const float*)p)[i] : __bfloat162float(((const bf16*)p)[i]);
}

// async global->LDS, 16B/lane; LDS base wave-uniform, lanes land linearly
__device__ __forceinline__ void gld16(const bf16* g, bf16* l) {
    __builtin_amdgcn_global_load_lds((const __attribute__((address_space(1))) void*)g,
                                     (__attribute__((address_space(3))) void*)l, 16, 0, 0);
}

// ---------------------------------------------------------------------------
__global__ __launch_bounds__(256) void cast_k(const void* __restrict__ x, float* __restrict__ h,
                                              const int* __restrict__ flagp) {
    bool f32 = (*flagp != 0);
    size_t i = (size_t)blockIdx.x * 256 + threadIdx.x;
    h[i] = ldf(x, i, f32);
}

// ---------------------------------------------------------------------------
// LayerNorm f32 rows(1024) -> bf16 (or external dtype when outExt)
__global__ __launch_bounds__(256) void ln_k(const float* __restrict__ in,
                                            const void* __restrict__ g, size_t goff,
                                            const void* __restrict__ be, size_t boff,
                                            void* __restrict__ out, int outExt,
                                            const int* __restrict__ flagp) {
    bool f32 = (*flagp != 0);
    int row = blockIdx.x, tid = threadIdx.x;
    const float* rp = in + (size_t)row * Dc;
    float4 v = *(const float4*)(rp + tid * 4);
    float s  = v.x + v.y + v.z + v.w;
    float sq = v.x * v.x + v.y * v.y + v.z * v.z + v.w * v.w;
    int w = tid >> 6, lane = tid & 63;
    #pragma unroll
    for (int off = 32; off >= 1; off >>= 1) {
        s  += __shfl_down(s, off);
        sq += __shfl_down(sq, off);
    }
    __shared__ float rs[4], rq[4];
    if (lane == 0) { rs[w] = s; rq[w] = sq; }
    __syncthreads();
    float S4 = rs[0] + rs[1] + rs[2] + rs[3];
    float Q4 = rq[0] + rq[1] + rq[2] + rq[3];
    float mean = S4 * (1.f / Dc);
    float var  = Q4 * (1.f / Dc) - mean * mean;
    float rstd = rsqrtf(var + 1e-5f);
    #pragma unroll
    for (int j = 0; j < 4; j++) {
        int c = tid * 4 + j;
        float xv = (&v.x)[j];
        float val = (xv - mean) * rstd * ldf(g, goff + c, f32) + ldf(be, boff + c, f32);
        size_t idx = (size_t)row * Dc + c;
        if (outExt && f32) ((float*)out)[idx] = val;
        else               ((bf16*)out)[idx] = __float2bfloat16(val);
    }
}

// ---------------------------------------------------------------------------
// Weight transpose+convert into BLOCKED PRE-SWIZZLED layout:
// W_t = [nTile][kTile][64n][64k], granule g of inner row n at slot g^(n&7).
// Each wave writes one fully contiguous 8KB tile. Read: 512B runs (64k x 256n).
// x-blocks: 0..255 Wq/Wk/Wv/Wo; 256..511 W1; 512..767 W2;
// 768: rel_k -> rkb [64][128] pad0, rel_v -> rvt [128][64] transposed pad0.
__global__ __launch_bounds__(256) void conv_k(const void* __restrict__ Wq, const void* __restrict__ Wk,
                                              const void* __restrict__ Wv, const void* __restrict__ Wo,
                                              const void* __restrict__ W1, const void* __restrict__ W2,
                                              const void* __restrict__ rk, const void* __restrict__ rv,
                                              char* __restrict__ slotBase, size_t slotStride,
                                              int layer0, int slotMul,
                                              const int* __restrict__ flagp) {
    bool f32 = (*flagp != 0);
    int l = layer0 + blockIdx.y;
    char* sp = slotBase + (size_t)(slotMul ? l : 0) * slotStride;
    bf16* Wqkv_t = (bf16*)sp;
    bf16* Wo_t   = (bf16*)(sp + (6ll << 20));
    bf16* W1_t   = (bf16*)(sp + (8ll << 20));
    bf16* W2_t   = (bf16*)(sp + (16ll << 20));
    bf16* rkb    = (bf16*)(sp + (24ll << 20));
    bf16* rvt    = (bf16*)(sp + (24ll << 20) + 16384);
    size_t wOff = (size_t)l * Dc * Dc, w1Off = (size_t)l * Dc * Fc, rOff = (size_t)l * Kc * DKc;

    int bid = blockIdx.x, tid = threadIdx.x;
    if (bid == 768) {
        for (int idx = tid; idx < 64 * DKc; idx += 256) {
            int rr = idx >> 7, d = idx & 127;
            rkb[idx] = (rr < Kc) ? __float2bfloat16(ldf(rk, rOff + (size_t)rr * DKc + d, f32))
                                 : __float2bfloat16(0.f);
        }
        for (int idx = tid; idx < DKc * 64; idx += 256) {
            int d = idx >> 6, rr = idx & 63;
            rvt[idx] = (rr < Kc) ? __float2bfloat16(ldf(rv, rOff + (size_t)rr * DKc + d, f32))
                                 : __float2bfloat16(0.f);
        }
        return;
    }
    const void* src; bf16* dst; int ldn, k0, n0, KT;
    if (bid < 256) {
        int m = bid >> 6, t = bid & 63;
        k0 = (t >> 2) * 64; n0 = (t & 3) * 256;
        src = (m == 0) ? Wq : (m == 1) ? Wk : (m == 2) ? Wv : Wo;
        src = (const void*)((const char*)src + wOff * (f32 ? 4 : 2));
        dst = (m < 3) ? (Wqkv_t + (size_t)m * Dc * Dc) : Wo_t;
        ldn = Dc; KT = 16;
    } else if (bid < 512) {
        int t = bid - 256;
        k0 = (t >> 4) * 64; n0 = (t & 15) * 256;
        src = (const void*)((const char*)W1 + w1Off * (f32 ? 4 : 2));
        dst = W1_t; ldn = Fc; KT = 16;
    } else {
        int t = bid - 512;
        k0 = (t >> 2) * 64; n0 = (t & 3) * 256;
        src = (const void*)((const char*)W2 + w1Off * (f32 ? 4 : 2));
        dst = W2_t; ldn = Dc; KT = 64;
    }
    __shared__ bf16 sT[64][264];
    int r = tid >> 2, seg = tid & 3;                 // k-row, 64-col segment
    if (f32) {
        const float* sp2 = (const float*)src + (size_t)(k0 + r) * ldn + n0 + seg * 64;
        #pragma unroll
        for (int c4 = 0; c4 < 4; c4++) {
            alignas(16) bf16 tmp[16];
            #pragma unroll
            for (int q = 0; q < 4; q++) {
                float4 fv = *(const float4*)(sp2 + c4 * 16 + q * 4);
                tmp[q * 4 + 0] = __float2bfloat16(fv.x);
                tmp[q * 4 + 1] = __float2bfloat16(fv.y);
                tmp[q * 4 + 2] = __float2bfloat16(fv.z);
                tmp[q * 4 + 3] = __float2bfloat16(fv.w);
            }
            *(int4v*)&sT[r][seg * 64 + c4 * 16]     = *(int4v*)tmp;
            *(int4v*)&sT[r][seg * 64 + c4 * 16 + 8] = *(int4v*)(tmp + 8);
        }
    } else {
        const bf16* sp2 = (const bf16*)src + (size_t)(k0 + r) * ldn + n0 + seg * 64;
        #pragma unroll
        for (int c4 = 0; c4 < 4; c4++) {
            *(int4v*)&sT[r][seg * 64 + c4 * 16]     = *(const int4v*)(sp2 + c4 * 16);
            *(int4v*)&sT[r][seg * 64 + c4 * 16 + 8] = *(const int4v*)(sp2 + c4 * 16 + 8);
        }
    }
    __syncthreads();
    // write: wave per 8KB dest tile, thread -> inner row n (128B, granule-permuted)
    int nt_i = tid >> 6, n = tid & 63;
    bf16* tileB = dst + ((((size_t)(n0 >> 6) + nt_i) * KT + (k0 >> 6)) << 12);
    alignas(16) bf16 outv[64];
    #pragma unroll
    for (int k = 0; k < 64; k++) outv[k] = sT[k][tid];
    bf16* dp = tileB + n * 64;
    #pragma unroll
    for (int g = 0; g < 8; g++)
        *(int4v*)(dp + ((g ^ (n & 7)) << 3)) = *(int4v*)(outv + g * 8);
}

// ---------------------------------------------------------------------------
// swizzled frag read: granule g at row r lives at slot g ^ (r&7)
__device__ __forceinline__ short8 frd(const bf16* s, int row, int g) {
    return *(const short8*)(s + (size_t)row * 64 + ((g ^ (row & 7)) << 3));
}

// 64x64-tile MFMA GEMM, BK=64, depth-2 prefetch (3 bufs) + counted vmcnt(4).
// A [m][k] row-major, staged via source-granule-swizzled gld16.
// B in BLOCKED PRE-SWIZZLED layout [nTile][KT][64][64] -> linear gld16 staging.
// 1-D grid, XCD-aware bijective decomposition (nx % 8 == 0).
// MODE 0: qkv cols<2048 -> qkv+bias; cols>=2048 -> vt transposed (+bias)
// MODE 1: outb = relu(A@B^T + bias)
// MODE 2: atomicAdd(outf, A@B^T + (kslice==0 ? bias : 0))
template <int MODE>
__global__ __launch_bounds__(256) void gemm2_k(const bf16* __restrict__ Ag, int lda,
                                               const bf16* __restrict__ Bt, int KT,
                                               const void* __restrict__ bA, const void* __restrict__ bB,
                                               const void* __restrict__ bC, size_t boff,
                                               float* __restrict__ outf,
                                               bf16* __restrict__ outb, bf16* __restrict__ vtp,
                                               int N, int Kd, int nx, int znum,
                                               const int* __restrict__ flagp) {
    bool f32e = (*flagp != 0);
    __shared__ bf16 sA[3][64][64];
    __shared__ bf16 sB[3][64][64];
    int tid = threadIdx.x, wv = tid >> 6, lane = tid & 63;

    // XCD-aware bijective decomposition (nx % 8 == 0 required)
    int bid = blockIdx.x;
    int c = bid & 7, j = bid >> 3;
    int npc = nx >> 3;
    int mz = 8 * znum;
    int nl = j / mz; int rem = j - nl * mz;
    int mtile = rem / znum; int kslice = rem - mtile * znum;
    int ntile = c * npc + nl;

    int row0 = mtile * 64;
    int nt = Kd / 64;
    const bf16* Ab = Ag + (size_t)kslice * Kd;
    const bf16* Bbase = Bt + (((size_t)ntile * KT + (size_t)kslice * nt) << 12);
    int wm = (wv >> 1) * 32, wn = (wv & 1) * 32;
    int lr = lane >> 3;
    int gsw = ((lane & 7) ^ lr) * 8;        // A: swizzled source granule offset
    int lc8 = (lane & 7) * 8;               // B: linear within blocked tile
    f32x4 acc[2][2] = {};

    auto stage = [&](int buf, int t) {
        const bf16* bt = Bbase + ((size_t)t << 12);
        #pragma unroll
        for (int cc = 0; cc < 2; ++cc) {
            int rr = 16 * wv + 8 * cc;
            gld16(Ab + (size_t)(row0 + rr + lr) * lda + t * 64 + gsw, &sA[buf][rr][0]);
            gld16(bt + (size_t)(rr + lr) * 64 + lc8, &sB[buf][rr][0]);
        }
    };
    stage(0, 0);
    if (nt > 1) { stage(1, 1); WAITV4; } else { WAITV0; }
    SBAR();

    int r16 = lane & 15, kq = lane >> 4;
    for (int t = 0; t < nt; ++t) {
        if (t + 2 < nt) stage((t + 2) % 3, t + 2);
        int cb = t % 3;
        const bf16* pa = &sA[cb][0][0];
        const bf16* pb = &sB[cb][0][0];
        #pragma unroll
        for (int ks = 0; ks < 2; ks++) {
            int g = ks * 4 + kq;
            short8 a0 = frd(pa, wm + r16, g);
            short8 a1 = frd(pa, wm + 16 + r16, g);
            short8 b0 = frd(pb, wn + r16, g);
            short8 b1 = frd(pb, wn + 16 + r16, g);
            acc[0][0] = __builtin_amdgcn_mfma_f32_16x16x32_bf16(a0, b0, acc[0][0], 0, 0, 0);
            acc[0][1] = __builtin_amdgcn_mfma_f32_16x16x32_bf16(a0, b1, acc[0][1], 0, 0, 0);
            acc[1][0] = __builtin_amdgcn_mfma_f32_16x16x32_bf16(a1, b0, acc[1][0], 0, 0, 0);
            acc[1][1] = __builtin_amdgcn_mfma_f32_16x16x32_bf16(a1, b1, acc[1][1], 0, 0, 0);
        }
        if (t + 2 < nt) { WAITV4; } else if (t + 1 < nt) { WAITV0; }
        SBAR();
    }

    int col0 = ntile * 64;
    #pragma unroll
    for (int mi = 0; mi < 2; mi++) {
        #pragma unroll
        for (int ni = 0; ni < 2; ni++) {
            int col = col0 + wn + ni * 16 + r16;
            if (MODE == 0) {
                int sel = col >> 10;
                const void* bp = (sel == 0) ? bA : (sel == 1) ? bB : bC;
                float bias = ldf(bp, boff + (col & 1023), f32e);
                if (sel < 2) {
                    #pragma unroll
                    for (int r = 0; r < 4; r++) {
                        int row = row0 + wm + mi * 16 + kq * 4 + r;
                        outb[(size_t)row * 3072 + col] = __float2bfloat16(acc[mi][ni][r] + bias);
                    }
                } else {
                    int hh = (col - 2048) >> 7, d = (col - 2048) & 127;
                    int b = row0 >> 8;
                    int s0 = (row0 & 255) + wm + mi * 16 + kq * 4;
                    alignas(8) bf16 pk[4];
                    #pragma unroll
                    for (int r = 0; r < 4; r++) pk[r] = __float2bfloat16(acc[mi][ni][r] + bias);
                    *(short4*)(vtp + (((size_t)(b * 8 + hh)) * 128 + d) * 256 + s0) = *(short4*)pk;
                }
            } else if (MODE == 1) {
                float bias = ldf(bA, boff + col, f32e);
                #pragma unroll
                for (int r = 0; r < 4; r++) {
                    int row = row0 + wm + mi * 16 + kq * 4 + r;
                    float tv = acc[mi][ni][r] + bias;
                    outb[(size_t)row * N + col] = __float2bfloat16(tv > 0.f ? tv : 0.f);
                }
            } else {
                float add = (kslice == 0) ? ldf(bA, boff + col, f32e) : 0.f;
                #pragma unroll
                for (int r = 0; r < 4; r++) {
                    int row = row0 + wm + mi * 16 + kq * 4 + r;
                    atomicAdd(&outf[(size_t)row * N + col], acc[mi][ni][r] + add);
                }
            }
        }
    }
}

// ---------------------------------------------------------------------------
// Fused attention, ONE WAVE PER BLOCK (64 threads), 16 q-rows per block:
// grid (16 qgroups, 16 z) = 256 blocks -> all 256 CUs busy. T5 setprio
// around MFMA clusters (role-diverse blocks per CU).
__global__ __launch_bounds__(64) void attn_k(const bf16* __restrict__ qkv,
                                             const bf16* __restrict__ vt,
                                             const bf16* __restrict__ rkb,
                                             const bf16* __restrict__ rvt,
                                             const int* __restrict__ relation,
                                             bf16* __restrict__ ob) {
    int z = blockIdx.y, b = z >> 3, h = z & 7;
    int q0 = blockIdx.x * 16;
    int lane = threadIdx.x;
    int l15 = lane & 15, l4 = lane >> 4;

    __shared__ float qr_s[16][48];
    __shared__ float bins_s[16][40];
    __shared__ bf16  Pl[16][264];
    __shared__ bf16  binb[16][64];

    for (int c = lane; c < 16 * 40; c += 64) bins_s[c / 40][c % 40] = 0.f;

    short8 qf[4];
    const bf16* qp = qkv + (size_t)(b * Sc + q0 + l15) * 3072 + h * DKc + l4 * 8;
    #pragma unroll
    for (int ks = 0; ks < 4; ks++) qf[ks] = *(const short8*)(qp + ks * 32);

    f32x4 sc[19];
    #pragma unroll
    for (int f = 0; f < 19; f++) sc[f] = f32x4{0.f, 0.f, 0.f, 0.f};
    const bf16* kbase = qkv + (size_t)(b * Sc) * 3072 + Dc + h * DKc;
    __builtin_amdgcn_s_setprio(1);
    #pragma unroll
    for (int f = 0; f < 16; f++) {
        #pragma unroll
        for (int ks = 0; ks < 4; ks++) {
            short8 kv = *(const short8*)(kbase + (size_t)(f * 16 + l15) * 3072 + ks * 32 + l4 * 8);
            sc[f] = __builtin_amdgcn_mfma_f32_16x16x32_bf16(qf[ks], kv, sc[f], 0, 0, 0);
        }
    }
    #pragma unroll
    for (int f = 0; f < 3; f++) {
        #pragma unroll
        for (int ks = 0; ks < 4; ks++) {
            short8 rv_ = *(const short8*)(rkb + (size_t)(f * 16 + l15) * DKc + ks * 32 + l4 * 8);
            sc[16 + f] = __builtin_amdgcn_mfma_f32_16x16x32_bf16(qf[ks], rv_, sc[16 + f], 0, 0, 0);
        }
    }
    __builtin_amdgcn_s_setprio(0);
    #pragma unroll
    for (int f = 0; f < 3; f++)
        #pragma unroll
        for (int r = 0; r < 4; r++)
            qr_s[l4 * 4 + r][f * 16 + l15] = sc[16 + f][r];
    __syncthreads();

    unsigned relpk[16];
    #pragma unroll
    for (int f = 0; f < 16; f++) {
        unsigned pk = 0;
        #pragma unroll
        for (int r = 0; r < 4; r++) {
            int rowl = l4 * 4 + r;
            int col = f * 16 + l15;
            int rel = relation[((size_t)b * Sc + q0 + rowl) * Sc + col];
            pk |= (unsigned)rel << (8 * r);
            sc[f][r] = (sc[f][r] + qr_s[rowl][rel]) * SCALE;
        }
        relpk[f] = pk;
    }
    float inv[4];
    #pragma unroll
    for (int r = 0; r < 4; r++) {
        float m = -3.0e38f;
        #pragma unroll
        for (int f = 0; f < 16; f++) m = fmaxf(m, sc[f][r]);
        m = fmaxf(m, __shfl_xor(m, 1)); m = fmaxf(m, __shfl_xor(m, 2));
        m = fmaxf(m, __shfl_xor(m, 4)); m = fmaxf(m, __shfl_xor(m, 8));
        float s = 0.f;
        #pragma unroll
        for (int f = 0; f < 16; f++) { float e = __expf(sc[f][r] - m); sc[f][r] = e; s += e; }
        s += __shfl_xor(s, 1); s += __shfl_xor(s, 2); s += __shfl_xor(s, 4); s += __shfl_xor(s, 8);
        inv[r] = 1.f / s;
    }
    #pragma unroll
    for (int f = 0; f < 16; f++) {
        #pragma unroll
        for (int r = 0; r < 4; r++) {
            int rowl = l4 * 4 + r;
            int col = f * 16 + l15;
            float p = sc[f][r] * inv[r];
            Pl[rowl][col] = __float2bfloat16(p);
            int rel = (relpk[f] >> (8 * r)) & 0xFF;
            atomicAdd(&bins_s[rowl][rel], p);
        }
    }
    __syncthreads();
    for (int c = lane; c < 16 * 64; c += 64) {
        int row = c >> 6, k = c & 63;
        binb[row][k] = __float2bfloat16((k < Kc) ? bins_s[row][k] : 0.f);
    }
    __syncthreads();

    f32x4 acc_o[8];
    #pragma unroll
    for (int df = 0; df < 8; df++) acc_o[df] = f32x4{0.f, 0.f, 0.f, 0.f};
    const bf16* vbase = vt + (size_t)z * DKc * Sc;
    __builtin_amdgcn_s_setprio(1);
    #pragma unroll
    for (int ks = 0; ks < 8; ks++) {
        short8 af = *(const short8*)&Pl[l15][ks * 32 + l4 * 8];
        #pragma unroll
        for (int df = 0; df < 8; df++) {
            short8 bv = *(const short8*)(vbase + (size_t)(df * 16 + l15) * Sc + ks * 32 + l4 * 8);
            acc_o[df] = __builtin_amdgcn_mfma_f32_16x16x32_bf16(af, bv, acc_o[df], 0, 0, 0);
        }
    }
    #pragma unroll
    for (int ks = 0; ks < 2; ks++) {
        short8 af = *(const short8*)&binb[l15][ks * 32 + l4 * 8];
        #pragma unroll
        for (int df = 0; df < 8; df++) {
            short8 bv = *(const short8*)(rvt + (size_t)(df * 16 + l15) * 64 + ks * 32 + l4 * 8);
            acc_o[df] = __builtin_amdgcn_mfma_f32_16x16x32_bf16(af, bv, acc_o[df], 0, 0, 0);
        }
    }
    __builtin_amdgcn_s_setprio(0);
    #pragma unroll
    for (int df = 0; df < 8; df++) {
        int col = df * 16 + l15;
        #pragma unroll
        for (int r = 0; r < 4; r++) {
            int rowl = l4 * 4 + r;
            ob[((size_t)(b * Sc + q0 + rowl) * Hc + h) * DKc + col] = __float2bfloat16(acc_o[df][r]);
        }
    }
}

// ---------------------------------------------------------------------------
extern "C" void kernel_launch(void* const* d_in, const int* in_sizes, int n_in,
                              void* d_out, int out_size, void* d_ws, size_t ws_size,
                              hipStream_t stream) {
    const void* x        = d_in[0];
    const int*  relation = (const int*)d_in[1];
    const void* Wq = d_in[3];  const void* bq = d_in[4];
    const void* Wk = d_in[5];  const void* bk = d_in[6];
    const void* Wv = d_in[7];  const void* bv = d_in[8];
    const void* Wo = d_in[9];  const void* bo = d_in[10];
    const void* g1 = d_in[11]; const void* be1 = d_in[12];
    const void* W1 = d_in[13]; const void* b1 = d_in[14];
    const void* W2 = d_in[15]; const void* b2 = d_in[16];
    const void* g2 = d_in[17]; const void* be2 = d_in[18];
    const void* relk = d_in[19]; const void* relv = d_in[20];
    const void* lnfg = d_in[21]; const void* lnfb = d_in[22];

    char* ws = (char*)d_ws;
    float* h    = (float*)(ws);                 // 2 MB
    bf16*  hn   = (bf16*)(ws + (2ll  << 20));   // 1 MB
    bf16*  qkv  = (bf16*)(ws + (3ll  << 20));   // 3 MB [512][3072] (v third unused)
    bf16*  vt   = (bf16*)(ws + (6ll  << 20));   // 1 MB [16][128][256]
    bf16*  ob   = (bf16*)(ws + (7ll  << 20));   // 1 MB
    bf16*  f1   = (bf16*)(ws + (8ll  << 20));   // 4 MB
    int*   flag = (int*)(ws + (12ll << 20));
    const size_t WBASE = 13ll << 20;
    const size_t WSTRIDE = 25ll << 20;          // per-layer transposed weights
    int nslot = (ws_size >= WBASE + 8 * WSTRIDE) ? 8 : 1;
    char* slotBase = ws + WBASE;
    // slot: Wqkv_t 6MB | Wo_t 2MB | W1_t 8MB | W2_t 8MB | rkb 16KB | rvt 16KB

    const int M = Bc * Sc; // 512

    detect_k<<<1, 256, 0, stream>>>((const unsigned short*)Wq, flag);
    cast_k<<<(Bc * Sc * Dc) / 256, 256, 0, stream>>>(x, h, flag);

    if (nslot == 8)
        conv_k<<<dim3(769, 8), 256, 0, stream>>>(Wq, Wk, Wv, Wo, W1, W2, relk, relv,
                                                 slotBase, WSTRIDE, 0, 1, flag);

    for (int l = 0; l < Lc; l++) {
        if (nslot == 1)
            conv_k<<<dim3(769, 1), 256, 0, stream>>>(Wq, Wk, Wv, Wo, W1, W2, relk, relv,
                                                     slotBase, WSTRIDE, l, 0, flag);
        char* sp = slotBase + (size_t)((nslot == 8) ? l : 0) * WSTRIDE;
        bf16* Wqkv_t = (bf16*)sp;
        bf16* Wo_t   = (bf16*)(sp + (6ll << 20));
        bf16* W1_t   = (bf16*)(sp + (8ll << 20));
        bf16* W2_t   = (bf16*)(sp + (16ll << 20));
        bf16* rkb    = (bf16*)(sp + (24ll << 20));
        bf16* rvt    = (bf16*)(sp + (24ll << 20) + 16384);
        size_t dOff = (size_t)l * Dc, fOff = (size_t)l * Fc;

        ln_k<<<M, 256, 0, stream>>>(h, g1, dOff, be1, dOff, hn, 0, flag);

        // QKV (+ fused V-transpose epilogue): 48 n-tiles x 8 m-tiles = 384 blocks
        gemm2_k<0><<<384, 256, 0, stream>>>(hn, Dc, Wqkv_t, 16, bq, bk, bv, dOff,
                                            nullptr, qkv, vt, 3072, Dc, 48, 1, flag);

        // attention: 256 single-wave blocks (16 qgroups x 16 z)
        attn_k<<<dim3(16, 16), 64, 0, stream>>>(qkv, vt, rkb, rvt, relation, ob);

        // h += o @ Wo + bo   (16 n x 8 m x splitK4 = 512 blocks)
        gemm2_k<2><<<512, 256, 0, stream>>>(ob, Dc, Wo_t, 16, bo, nullptr, nullptr, dOff,
                                            h, nullptr, nullptr, Dc, 256, 16, 4, flag);

        ln_k<<<M, 256, 0, stream>>>(h, g2, dOff, be2, dOff, hn, 0, flag);

        // f1 = relu(hn @ W1 + b1): 64 n x 8 m = 512 blocks
        gemm2_k<1><<<512, 256, 0, stream>>>(hn, Dc, W1_t, 16, b1, nullptr, nullptr, fOff,
                                            nullptr, f1, nullptr, Fc, Dc, 64, 1, flag);

        // h += f1 @ W2 + b2  (16 n x 8 m x splitK4 = 512 blocks)
        gemm2_k<2><<<512, 256, 0, stream>>>(f1, Fc, W2_t, 64, b2, nullptr, nullptr, dOff,
                                            h, nullptr, nullptr, Dc, 1024, 16, 4, flag);
    }

    ln_k<<<M, 256, 0, stream>>>(h, lnfg, 0, lnfb, 0, d_out, 1, flag);
}

// Round 16
// 862.670 us; speedup vs baseline: 1.1541x; 1.0608x over previous
//
#include <hip/hip_runtime.h>
#include <hip/hip_bf16.h>

typedef __hip_bfloat16 bf16;
typedef __attribute__((ext_vector_type(8))) short short8;   // 8 bf16 MFMA frag
typedef __attribute__((ext_vector_type(4))) float f32x4;
typedef __attribute__((ext_vector_type(4))) int  int4v;

constexpr int Bc = 2, Sc = 256, Dc = 1024, Hc = 8, DKc = 128, Fc = 4096, Lc = 8, Kc = 37;
constexpr float SCALE = 0.08838834764831845f; // 1/sqrt(128)

#define WAITV4 asm volatile("s_waitcnt vmcnt(4)" ::: "memory")
#define WAITV0 asm volatile("s_waitcnt vmcnt(0)" ::: "memory")
#define SBAR() do { __builtin_amdgcn_sched_barrier(0); __builtin_amdgcn_s_barrier(); } while (0)

// ---------------------------------------------------------------------------
__global__ __launch_bounds__(256) void detect_k(const unsigned short* __restrict__ w,
                                                int* __restrict__ flag) {
    __shared__ int cnt;
    if (threadIdx.x == 0) cnt = 0;
    __syncthreads();
    int ok = 0;
    #pragma unroll
    for (int j = 0; j < 16; j++) {
        unsigned short u = w[threadIdx.x * 16 + j];
        int e = (u >> 7) & 0xFF;
        ok += (e >= 100 && e <= 131) ? 1 : 0;
    }
    atomicAdd(&cnt, ok);
    __syncthreads();
    if (threadIdx.x == 0) *flag = (cnt < 3500) ? 1 : 0;  // 1 => external f32
}

__device__ __forceinline__ float ldf(const void* p, size_t i, bool f32) {
    return f32 ? ((const float*)p)[i] : __bfloat162float(((const bf16*)p)[i]);
}

// async global->LDS, 16B/lane; LDS base wave-uniform, lanes land linearly
__device__ __forceinline__ void gld16(const bf16* g, bf16* l) {
    __builtin_amdgcn_global_load_lds((const __attribute__((address_space(1))) void*)g,
                                     (__attribute__((address_space(3))) void*)l, 16, 0, 0);
}

// ---------------------------------------------------------------------------
__global__ __launch_bounds__(256) void cast_k(const void* __restrict__ x, float* __restrict__ h,
                                              const int* __restrict__ flagp) {
    bool f32 = (*flagp != 0);
    size_t i = (size_t)blockIdx.x * 256 + threadIdx.x;
    h[i] = ldf(x, i, f32);
}

// ---------------------------------------------------------------------------
// LayerNorm f32 rows(1024) -> bf16 (or external dtype when outExt)
__global__ __launch_bounds__(256) void ln_k(const float* __restrict__ in,
                                            const void* __restrict__ g, size_t goff,
                                            const void* __restrict__ be, size_t boff,
                                            void* __restrict__ out, int outExt,
                                            const int* __restrict__ flagp) {
    bool f32 = (*flagp != 0);
    int row = blockIdx.x, tid = threadIdx.x;
    const float* rp = in + (size_t)row * Dc;
    float4 v = *(const float4*)(rp + tid * 4);
    float s  = v.x + v.y + v.z + v.w;
    float sq = v.x * v.x + v.y * v.y + v.z * v.z + v.w * v.w;
    int w = tid >> 6, lane = tid & 63;
    #pragma unroll
    for (int off = 32; off >= 1; off >>= 1) {
        s  += __shfl_down(s, off);
        sq += __shfl_down(sq, off);
    }
    __shared__ float rs[4], rq[4];
    if (lane == 0) { rs[w] = s; rq[w] = sq; }
    __syncthreads();
    float S4 = rs[0] + rs[1] + rs[2] + rs[3];
    float Q4 = rq[0] + rq[1] + rq[2] + rq[3];
    float mean = S4 * (1.f / Dc);
    float var  = Q4 * (1.f / Dc) - mean * mean;
    float rstd = rsqrtf(var + 1e-5f);
    #pragma unroll
    for (int j = 0; j < 4; j++) {
        int c = tid * 4 + j;
        float xv = (&v.x)[j];
        float val = (xv - mean) * rstd * ldf(g, goff + c, f32) + ldf(be, boff + c, f32);
        size_t idx = (size_t)row * Dc + c;
        if (outExt && f32) ((float*)out)[idx] = val;
        else               ((bf16*)out)[idx] = __float2bfloat16(val);
    }
}

// ---------------------------------------------------------------------------
// Weight transpose+convert into BLOCKED PRE-SWIZZLED layout:
// W_t = [nTile][kTile][64n][64k], granule g of inner row n at slot g^(n&7).
// Each wave writes one fully contiguous 8KB tile. Read: 512B runs (64k x 256n).
// x-blocks: 0..255 Wq/Wk/Wv/Wo; 256..511 W1; 512..767 W2;
// 768: rel_k -> rkb [64][128] pad0, rel_v -> rvt [128][64] transposed pad0.
__global__ __launch_bounds__(256) void conv_k(const void* __restrict__ Wq, const void* __restrict__ Wk,
                                              const void* __restrict__ Wv, const void* __restrict__ Wo,
                                              const void* __restrict__ W1, const void* __restrict__ W2,
                                              const void* __restrict__ rk, const void* __restrict__ rv,
                                              char* __restrict__ slotBase, size_t slotStride,
                                              int layer0, int slotMul,
                                              const int* __restrict__ flagp) {
    bool f32 = (*flagp != 0);
    int l = layer0 + blockIdx.y;
    char* sp = slotBase + (size_t)(slotMul ? l : 0) * slotStride;
    bf16* Wqkv_t = (bf16*)sp;
    bf16* Wo_t   = (bf16*)(sp + (6ll << 20));
    bf16* W1_t   = (bf16*)(sp + (8ll << 20));
    bf16* W2_t   = (bf16*)(sp + (16ll << 20));
    bf16* rkb    = (bf16*)(sp + (24ll << 20));
    bf16* rvt    = (bf16*)(sp + (24ll << 20) + 16384);
    size_t wOff = (size_t)l * Dc * Dc, w1Off = (size_t)l * Dc * Fc, rOff = (size_t)l * Kc * DKc;

    int bid = blockIdx.x, tid = threadIdx.x;
    if (bid == 768) {
        for (int idx = tid; idx < 64 * DKc; idx += 256) {
            int rr = idx >> 7, d = idx & 127;
            rkb[idx] = (rr < Kc) ? __float2bfloat16(ldf(rk, rOff + (size_t)rr * DKc + d, f32))
                                 : __float2bfloat16(0.f);
        }
        for (int idx = tid; idx < DKc * 64; idx += 256) {
            int d = idx >> 6, rr = idx & 63;
            rvt[idx] = (rr < Kc) ? __float2bfloat16(ldf(rv, rOff + (size_t)rr * DKc + d, f32))
                                 : __float2bfloat16(0.f);
        }
        return;
    }
    const void* src; bf16* dst; int ldn, k0, n0, KT;
    if (bid < 256) {
        int m = bid >> 6, t = bid & 63;
        k0 = (t >> 2) * 64; n0 = (t & 3) * 256;
        src = (m == 0) ? Wq : (m == 1) ? Wk : (m == 2) ? Wv : Wo;
        src = (const void*)((const char*)src + wOff * (f32 ? 4 : 2));
        dst = (m < 3) ? (Wqkv_t + (size_t)m * Dc * Dc) : Wo_t;
        ldn = Dc; KT = 16;
    } else if (bid < 512) {
        int t = bid - 256;
        k0 = (t >> 4) * 64; n0 = (t & 15) * 256;
        src = (const void*)((const char*)W1 + w1Off * (f32 ? 4 : 2));
        dst = W1_t; ldn = Fc; KT = 16;
    } else {
        int t = bid - 512;
        k0 = (t >> 2) * 64; n0 = (t & 3) * 256;
        src = (const void*)((const char*)W2 + w1Off * (f32 ? 4 : 2));
        dst = W2_t; ldn = Dc; KT = 64;
    }
    __shared__ bf16 sT[64][264];
    int r = tid >> 2, seg = tid & 3;                 // k-row, 64-col segment
    if (f32) {
        const float* sp2 = (const float*)src + (size_t)(k0 + r) * ldn + n0 + seg * 64;
        #pragma unroll
        for (int c4 = 0; c4 < 4; c4++) {
            alignas(16) bf16 tmp[16];
            #pragma unroll
            for (int q = 0; q < 4; q++) {
                float4 fv = *(const float4*)(sp2 + c4 * 16 + q * 4);
                tmp[q * 4 + 0] = __float2bfloat16(fv.x);
                tmp[q * 4 + 1] = __float2bfloat16(fv.y);
                tmp[q * 4 + 2] = __float2bfloat16(fv.z);
                tmp[q * 4 + 3] = __float2bfloat16(fv.w);
            }
            *(int4v*)&sT[r][seg * 64 + c4 * 16]     = *(int4v*)tmp;
            *(int4v*)&sT[r][seg * 64 + c4 * 16 + 8] = *(int4v*)(tmp + 8);
        }
    } else {
        const bf16* sp2 = (const bf16*)src + (size_t)(k0 + r) * ldn + n0 + seg * 64;
        #pragma unroll
        for (int c4 = 0; c4 < 4; c4++) {
            *(int4v*)&sT[r][seg * 64 + c4 * 16]     = *(const int4v*)(sp2 + c4 * 16);
            *(int4v*)&sT[r][seg * 64 + c4 * 16 + 8] = *(const int4v*)(sp2 + c4 * 16 + 8);
        }
    }
    __syncthreads();
    // write: wave per 8KB dest tile, thread -> inner row n (128B, granule-permuted)
    int nt_i = tid >> 6, n = tid & 63;
    bf16* tileB = dst + ((((size_t)(n0 >> 6) + nt_i) * KT + (k0 >> 6)) << 12);
    alignas(16) bf16 outv[64];
    #pragma unroll
    for (int k = 0; k < 64; k++) outv[k] = sT[k][tid];
    bf16* dp = tileB + n * 64;
    #pragma unroll
    for (int g = 0; g < 8; g++)
        *(int4v*)(dp + ((g ^ (n & 7)) << 3)) = *(int4v*)(outv + g * 8);
}

// ---------------------------------------------------------------------------
// swizzled frag read: granule g at row r lives at slot g ^ (r&7)
__device__ __forceinline__ short8 frd(const bf16* s, int row, int g) {
    return *(const short8*)(s + (size_t)row * 64 + ((g ^ (row & 7)) << 3));
}

// 64x64-tile MFMA GEMM, BK=64, depth-2 prefetch (3 bufs) + counted vmcnt(4).
// A [m][k] row-major, staged via source-granule-swizzled gld16.
// B in BLOCKED PRE-SWIZZLED layout [nTile][KT][64][64] -> linear gld16 staging.
// 1-D grid, XCD-aware bijective decomposition (nx % 8 == 0).
// MODE 0: qkv cols<2048 -> qkv+bias; cols>=2048 -> vt transposed (+bias)
// MODE 1: outb = relu(A@B^T + bias)
// MODE 2: atomicAdd(outf, A@B^T + (kslice==0 ? bias : 0))
template <int MODE>
__global__ __launch_bounds__(256) void gemm2_k(const bf16* __restrict__ Ag, int lda,
                                               const bf16* __restrict__ Bt, int KT,
                                               const void* __restrict__ bA, const void* __restrict__ bB,
                                               const void* __restrict__ bC, size_t boff,
                                               float* __restrict__ outf,
                                               bf16* __restrict__ outb, bf16* __restrict__ vtp,
                                               int N, int Kd, int nx, int znum,
                                               const int* __restrict__ flagp) {
    bool f32e = (*flagp != 0);
    __shared__ bf16 sA[3][64][64];
    __shared__ bf16 sB[3][64][64];
    int tid = threadIdx.x, wv = tid >> 6, lane = tid & 63;

    // XCD-aware bijective decomposition (nx % 8 == 0 required)
    int bid = blockIdx.x;
    int c = bid & 7, j = bid >> 3;
    int npc = nx >> 3;
    int mz = 8 * znum;
    int nl = j / mz; int rem = j - nl * mz;
    int mtile = rem / znum; int kslice = rem - mtile * znum;
    int ntile = c * npc + nl;

    int row0 = mtile * 64;
    int nt = Kd / 64;
    const bf16* Ab = Ag + (size_t)kslice * Kd;
    const bf16* Bbase = Bt + (((size_t)ntile * KT + (size_t)kslice * nt) << 12);
    int wm = (wv >> 1) * 32, wn = (wv & 1) * 32;
    int lr = lane >> 3;
    int gsw = ((lane & 7) ^ lr) * 8;        // A: swizzled source granule offset
    int lc8 = (lane & 7) * 8;               // B: linear within blocked tile
    f32x4 acc[2][2] = {};

    auto stage = [&](int buf, int t) {
        const bf16* bt = Bbase + ((size_t)t << 12);
        #pragma unroll
        for (int cc = 0; cc < 2; ++cc) {
            int rr = 16 * wv + 8 * cc;
            gld16(Ab + (size_t)(row0 + rr + lr) * lda + t * 64 + gsw, &sA[buf][rr][0]);
            gld16(bt + (size_t)(rr + lr) * 64 + lc8, &sB[buf][rr][0]);
        }
    };
    stage(0, 0);
    if (nt > 1) { stage(1, 1); WAITV4; } else { WAITV0; }
    SBAR();

    int r16 = lane & 15, kq = lane >> 4;
    for (int t = 0; t < nt; ++t) {
        if (t + 2 < nt) stage((t + 2) % 3, t + 2);
        int cb = t % 3;
        const bf16* pa = &sA[cb][0][0];
        const bf16* pb = &sB[cb][0][0];
        #pragma unroll
        for (int ks = 0; ks < 2; ks++) {
            int g = ks * 4 + kq;
            short8 a0 = frd(pa, wm + r16, g);
            short8 a1 = frd(pa, wm + 16 + r16, g);
            short8 b0 = frd(pb, wn + r16, g);
            short8 b1 = frd(pb, wn + 16 + r16, g);
            acc[0][0] = __builtin_amdgcn_mfma_f32_16x16x32_bf16(a0, b0, acc[0][0], 0, 0, 0);
            acc[0][1] = __builtin_amdgcn_mfma_f32_16x16x32_bf16(a0, b1, acc[0][1], 0, 0, 0);
            acc[1][0] = __builtin_amdgcn_mfma_f32_16x16x32_bf16(a1, b0, acc[1][0], 0, 0, 0);
            acc[1][1] = __builtin_amdgcn_mfma_f32_16x16x32_bf16(a1, b1, acc[1][1], 0, 0, 0);
        }
        if (t + 2 < nt) { WAITV4; } else if (t + 1 < nt) { WAITV0; }
        SBAR();
    }

    int col0 = ntile * 64;
    #pragma unroll
    for (int mi = 0; mi < 2; mi++) {
        #pragma unroll
        for (int ni = 0; ni < 2; ni++) {
            int col = col0 + wn + ni * 16 + r16;
            if (MODE == 0) {
                int sel = col >> 10;
                const void* bp = (sel == 0) ? bA : (sel == 1) ? bB : bC;
                float bias = ldf(bp, boff + (col & 1023), f32e);
                if (sel < 2) {
                    #pragma unroll
                    for (int r = 0; r < 4; r++) {
                        int row = row0 + wm + mi * 16 + kq * 4 + r;
                        outb[(size_t)row * 3072 + col] = __float2bfloat16(acc[mi][ni][r] + bias);
                    }
                } else {
                    int hh = (col - 2048) >> 7, d = (col - 2048) & 127;
                    int b = row0 >> 8;
                    int s0 = (row0 & 255) + wm + mi * 16 + kq * 4;
                    alignas(8) bf16 pk[4];
                    #pragma unroll
                    for (int r = 0; r < 4; r++) pk[r] = __float2bfloat16(acc[mi][ni][r] + bias);
                    *(short4*)(vtp + (((size_t)(b * 8 + hh)) * 128 + d) * 256 + s0) = *(short4*)pk;
                }
            } else if (MODE == 1) {
                float bias = ldf(bA, boff + col, f32e);
                #pragma unroll
                for (int r = 0; r < 4; r++) {
                    int row = row0 + wm + mi * 16 + kq * 4 + r;
                    float tv = acc[mi][ni][r] + bias;
                    outb[(size_t)row * N + col] = __float2bfloat16(tv > 0.f ? tv : 0.f);
                }
            } else {
                float add = (kslice == 0) ? ldf(bA, boff + col, f32e) : 0.f;
                #pragma unroll
                for (int r = 0; r < 4; r++) {
                    int row = row0 + wm + mi * 16 + kq * 4 + r;
                    atomicAdd(&outf[(size_t)row * N + col], acc[mi][ni][r] + add);
                }
            }
        }
    }
}

// ---------------------------------------------------------------------------
// Fused attention, ONE WAVE PER BLOCK (64 threads), 16 q-rows per block:
// grid (16 qgroups, 16 z) = 256 blocks -> all 256 CUs busy.
__global__ __launch_bounds__(64) void attn_k(const bf16* __restrict__ qkv,
                                             const bf16* __restrict__ vt,
                                             const bf16* __restrict__ rkb,
                                             const bf16* __restrict__ rvt,
                                             const int* __restrict__ relation,
                                             bf16* __restrict__ ob) {
    int z = blockIdx.y, b = z >> 3, h = z & 7;
    int q0 = blockIdx.x * 16;
    int lane = threadIdx.x;
    int l15 = lane & 15, l4 = lane >> 4;

    __shared__ float qr_s[16][48];
    __shared__ float bins_s[16][40];
    __shared__ bf16  Pl[16][264];
    __shared__ bf16  binb[16][64];

    for (int c = lane; c < 16 * 40; c += 64) bins_s[c / 40][c % 40] = 0.f;

    short8 qf[4];
    const bf16* qp = qkv + (size_t)(b * Sc + q0 + l15) * 3072 + h * DKc + l4 * 8;
    #pragma unroll
    for (int ks = 0; ks < 4; ks++) qf[ks] = *(const short8*)(qp + ks * 32);

    f32x4 sc[19];
    #pragma unroll
    for (int f = 0; f < 19; f++) sc[f] = f32x4{0.f, 0.f, 0.f, 0.f};
    const bf16* kbase = qkv + (size_t)(b * Sc) * 3072 + Dc + h * DKc;
    #pragma unroll
    for (int f = 0; f < 16; f++) {
        #pragma unroll
        for (int ks = 0; ks < 4; ks++) {
            short8 kv = *(const short8*)(kbase + (size_t)(f * 16 + l15) * 3072 + ks * 32 + l4 * 8);
            sc[f] = __builtin_amdgcn_mfma_f32_16x16x32_bf16(qf[ks], kv, sc[f], 0, 0, 0);
        }
    }
    #pragma unroll
    for (int f = 0; f < 3; f++) {
        #pragma unroll
        for (int ks = 0; ks < 4; ks++) {
            short8 rv_ = *(const short8*)(rkb + (size_t)(f * 16 + l15) * DKc + ks * 32 + l4 * 8);
            sc[16 + f] = __builtin_amdgcn_mfma_f32_16x16x32_bf16(qf[ks], rv_, sc[16 + f], 0, 0, 0);
        }
    }
    #pragma unroll
    for (int f = 0; f < 3; f++)
        #pragma unroll
        for (int r = 0; r < 4; r++)
            qr_s[l4 * 4 + r][f * 16 + l15] = sc[16 + f][r];
    __syncthreads();

    unsigned relpk[16];
    #pragma unroll
    for (int f = 0; f < 16; f++) {
        unsigned pk = 0;
        #pragma unroll
        for (int r = 0; r < 4; r++) {
            int rowl = l4 * 4 + r;
            int col = f * 16 + l15;
            int rel = relation[((size_t)b * Sc + q0 + rowl) * Sc + col];
            pk |= (unsigned)rel << (8 * r);
            sc[f][r] = (sc[f][r] + qr_s[rowl][rel]) * SCALE;
        }
        relpk[f] = pk;
    }
    float inv[4];
    #pragma unroll
    for (int r = 0; r < 4; r++) {
        float m = -3.0e38f;
        #pragma unroll
        for (int f = 0; f < 16; f++) m = fmaxf(m, sc[f][r]);
        m = fmaxf(m, __shfl_xor(m, 1)); m = fmaxf(m, __shfl_xor(m, 2));
        m = fmaxf(m, __shfl_xor(m, 4)); m = fmaxf(m, __shfl_xor(m, 8));
        float s = 0.f;
        #pragma unroll
        for (int f = 0; f < 16; f++) { float e = __expf(sc[f][r] - m); sc[f][r] = e; s += e; }
        s += __shfl_xor(s, 1); s += __shfl_xor(s, 2); s += __shfl_xor(s, 4); s += __shfl_xor(s, 8);
        inv[r] = 1.f / s;
    }
    #pragma unroll
    for (int f = 0; f < 16; f++) {
        #pragma unroll
        for (int r = 0; r < 4; r++) {
            int rowl = l4 * 4 + r;
            int col = f * 16 + l15;
            float p = sc[f][r] * inv[r];
            Pl[rowl][col] = __float2bfloat16(p);
            int rel = (relpk[f] >> (8 * r)) & 0xFF;
            atomicAdd(&bins_s[rowl][rel], p);
        }
    }
    __syncthreads();
    for (int c = lane; c < 16 * 64; c += 64) {
        int row = c >> 6, k = c & 63;
        binb[row][k] = __float2bfloat16((k < Kc) ? bins_s[row][k] : 0.f);
    }
    __syncthreads();

    f32x4 acc_o[8];
    #pragma unroll
    for (int df = 0; df < 8; df++) acc_o[df] = f32x4{0.f, 0.f, 0.f, 0.f};
    const bf16* vbase = vt + (size_t)z * DKc * Sc;
    #pragma unroll
    for (int ks = 0; ks < 8; ks++) {
        short8 af = *(const short8*)&Pl[l15][ks * 32 + l4 * 8];
        #pragma unroll
        for (int df = 0; df < 8; df++) {
            short8 bv = *(const short8*)(vbase + (size_t)(df * 16 + l15) * Sc + ks * 32 + l4 * 8);
            acc_o[df] = __builtin_amdgcn_mfma_f32_16x16x32_bf16(af, bv, acc_o[df], 0, 0, 0);
        }
    }
    #pragma unroll
    for (int ks = 0; ks < 2; ks++) {
        short8 af = *(const short8*)&binb[l15][ks * 32 + l4 * 8];
        #pragma unroll
        for (int df = 0; df < 8; df++) {
            short8 bv = *(const short8*)(rvt + (size_t)(df * 16 + l15) * 64 + ks * 32 + l4 * 8);
            acc_o[df] = __builtin_amdgcn_mfma_f32_16x16x32_bf16(af, bv, acc_o[df], 0, 0, 0);
        }
    }
    #pragma unroll
    for (int df = 0; df < 8; df++) {
        int col = df * 16 + l15;
        #pragma unroll
        for (int r = 0; r < 4; r++) {
            int rowl = l4 * 4 + r;
            ob[((size_t)(b * Sc + q0 + rowl) * Hc + h) * DKc + col] = __float2bfloat16(acc_o[df][r]);
        }
    }
}

// ---------------------------------------------------------------------------
extern "C" void kernel_launch(void* const* d_in, const int* in_sizes, int n_in,
                              void* d_out, int out_size, void* d_ws, size_t ws_size,
                              hipStream_t stream) {
    const void* x        = d_in[0];
    const int*  relation = (const int*)d_in[1];
    const void* Wq = d_in[3];  const void* bq = d_in[4];
    const void* Wk = d_in[5];  const void* bk = d_in[6];
    const void* Wv = d_in[7];  const void* bv = d_in[8];
    const void* Wo = d_in[9];  const void* bo = d_in[10];
    const void* g1 = d_in[11]; const void* be1 = d_in[12];
    const void* W1 = d_in[13]; const void* b1 = d_in[14];
    const void* W2 = d_in[15]; const void* b2 = d_in[16];
    const void* g2 = d_in[17]; const void* be2 = d_in[18];
    const void* relk = d_in[19]; const void* relv = d_in[20];
    const void* lnfg = d_in[21]; const void* lnfb = d_in[22];

    char* ws = (char*)d_ws;
    float* h    = (float*)(ws);                 // 2 MB
    bf16*  hn   = (bf16*)(ws + (2ll  << 20));   // 1 MB
    bf16*  qkv  = (bf16*)(ws + (3ll  << 20));   // 3 MB [512][3072] (v third unused)
    bf16*  vt   = (bf16*)(ws + (6ll  << 20));   // 1 MB [16][128][256]
    bf16*  ob   = (bf16*)(ws + (7ll  << 20));   // 1 MB
    bf16*  f1   = (bf16*)(ws + (8ll  << 20));   // 4 MB
    int*   flag = (int*)(ws + (12ll << 20));
    const size_t WBASE = 13ll << 20;
    const size_t WSTRIDE = 25ll << 20;          // per-layer transposed weights
    int nslot = (ws_size >= WBASE + 8 * WSTRIDE) ? 8 : 1;
    char* slotBase = ws + WBASE;
    // slot: Wqkv_t 6MB | Wo_t 2MB | W1_t 8MB | W2_t 8MB | rkb 16KB | rvt 16KB

    const int M = Bc * Sc; // 512

    detect_k<<<1, 256, 0, stream>>>((const unsigned short*)Wq, flag);
    cast_k<<<(Bc * Sc * Dc) / 256, 256, 0, stream>>>(x, h, flag);

    if (nslot == 8)
        conv_k<<<dim3(769, 8), 256, 0, stream>>>(Wq, Wk, Wv, Wo, W1, W2, relk, relv,
                                                 slotBase, WSTRIDE, 0, 1, flag);

    for (int l = 0; l < Lc; l++) {
        if (nslot == 1)
            conv_k<<<dim3(769, 1), 256, 0, stream>>>(Wq, Wk, Wv, Wo, W1, W2, relk, relv,
                                                     slotBase, WSTRIDE, l, 0, flag);
        char* sp = slotBase + (size_t)((nslot == 8) ? l : 0) * WSTRIDE;
        bf16* Wqkv_t = (bf16*)sp;
        bf16* Wo_t   = (bf16*)(sp + (6ll << 20));
        bf16* W1_t   = (bf16*)(sp + (8ll << 20));
        bf16* W2_t   = (bf16*)(sp + (16ll << 20));
        bf16* rkb    = (bf16*)(sp + (24ll << 20));
        bf16* rvt    = (bf16*)(sp + (24ll << 20) + 16384);
        size_t dOff = (size_t)l * Dc, fOff = (size_t)l * Fc;

        ln_k<<<M, 256, 0, stream>>>(h, g1, dOff, be1, dOff, hn, 0, flag);

        // QKV (+ fused V-transpose epilogue): 48 n-tiles x 8 m-tiles = 384 blocks
        gemm2_k<0><<<384, 256, 0, stream>>>(hn, Dc, Wqkv_t, 16, bq, bk, bv, dOff,
                                            nullptr, qkv, vt, 3072, Dc, 48, 1, flag);

        // attention: 256 single-wave blocks (16 qgroups x 16 z)
        attn_k<<<dim3(16, 16), 64, 0, stream>>>(qkv, vt, rkb, rvt, relation, ob);

        // h += o @ Wo + bo   (16 n x 8 m x splitK4 = 512 blocks)
        gemm2_k<2><<<512, 256, 0, stream>>>(ob, Dc, Wo_t, 16, bo, nullptr, nullptr, dOff,
                                            h, nullptr, nullptr, Dc, 256, 16, 4, flag);

        ln_k<<<M, 256, 0, stream>>>(h, g2, dOff, be2, dOff, hn, 0, flag);

        // f1 = relu(hn @ W1 + b1): 64 n x 8 m = 512 blocks
        gemm2_k<1><<<512, 256, 0, stream>>>(hn, Dc, W1_t, 16, b1, nullptr, nullptr, fOff,
                                            nullptr, f1, nullptr, Fc, Dc, 64, 1, flag);

        // h += f1 @ W2 + b2  (16 n x 8 m x splitK4 = 512 blocks)
        gemm2_k<2><<<512, 256, 0, stream>>>(f1, Fc, W2_t, 64, b2, nullptr, nullptr, dOff,
                                            h, nullptr, nullptr, Dc, 1024, 16, 4, flag);
    }

    ln_k<<<M, 256, 0, stream>>>(h, lnfg, 0, lnfb, 0, d_out, 1, flag);
}